// Round 12
// baseline (1707.395 us; speedup 1.0000x reference)
//
#include <hip/hip_runtime.h>
#include <hip/hip_bf16.h>
#include <stdint.h>

#define T_STEPS 512
#define BATCH   128
#define IN      512
#define HID     1024
#define OUTN    256

typedef __bf16 bf16x8 __attribute__((ext_vector_type(8)));
typedef float  f32x4  __attribute__((ext_vector_type(4)));
typedef unsigned short us8 __attribute__((ext_vector_type(8)));
typedef unsigned int   ui4 __attribute__((ext_vector_type(4)));

__device__ __forceinline__ unsigned short f2bf(float f) {
    uint32_t u = __float_as_uint(f);
    uint32_t r = (u + 0x7fffu + ((u >> 16) & 1u)) >> 16;   // RNE
    return (unsigned short)r;
}

// Agent-coherent 16B load (bypass L1+L2, read at LLC). Early-clobber dest.
__device__ __forceinline__ ui4 ld_u128_agent(const void* p) {
    ui4 v;
    asm volatile("global_load_dwordx4 %0, %1, off sc0 sc1"
                 : "=&v"(v) : "v"(p) : "memory");
    return v;
}
// Plain 16B load, issue-pinned (claimed by explicit vmcnt later).
__device__ __forceinline__ float4 ld_f128(const void* p) {
    float4 v;
    asm volatile("global_load_dwordx4 %0, %1, off"
                 : "=&v"(v) : "v"(p) : "memory");
    return v;
}

// Swizzled LDS fragment load: 16B at row*stride + (kbyte ^ ((row&7)<<4))
__device__ __forceinline__ bf16x8 ld_frag(const unsigned short* smem, int row, int kbyte, int rowstride) {
    int off = row * rowstride + (kbyte ^ ((row & 7) << 4));
    return *reinterpret_cast<const bf16x8*>(reinterpret_cast<const char*>(smem) + off);
}

__global__ __launch_bounds__(512, 1) void rnn_persistent(
    const float* __restrict__ seqs, const float* __restrict__ W_ih,
    const float* __restrict__ W_hh, const float* __restrict__ b_ih,
    const float* __restrict__ b_hh, const float* __restrict__ W_fc,
    const float* __restrict__ b_fc, float* __restrict__ out,
    unsigned short* __restrict__ hbuf,   // [2][128][1024] bf16 ring, row-major
    float* __restrict__ hfinal,          // [128][1024] fp32
    unsigned int* __restrict__ flags)    // [8][16] steps-completed per WG, zeroed
{
    const int tid   = threadIdx.x;
    const int lane  = tid & 63;
    const int wv    = tid >> 6;          // wave 0..7
    const int kteam = wv & 3;            // K-split 0..3 (same as R4's 4-way)
    const int chalf = wv >> 2;           // col half 0..1 (32 cols each)
    const int wg    = blockIdx.x;
    const int g     = wg >> 4;           // batch group 0..7 (rows g*16..+15)
    const int w     = wg & 15;           // col slice (cols w*64..+63)
    const int gr0   = g * 16;
    const int c0    = w * 64;
    const int ln15  = lane & 15;
    const int lk    = lane >> 4;

    __shared__ unsigned short xtile[16 * 512];   // 16KB, swizzled bf16
    __shared__ unsigned short htile[16 * 1024];  // 32KB, swizzled bf16
    __shared__ float red[4][16][66];             // K-team partials (+pad), 16.9KB
    __shared__ float biasS[64];

    // ---- init: weight B-fragments into registers (R6-proven layout) ----
    bf16x8 wih[2][4];
    bf16x8 whh[2][8];
    #pragma unroll
    for (int nt = 0; nt < 2; nt++) {
        const int j = c0 + chalf * 32 + nt * 16 + ln15;
        #pragma unroll
        for (int s = 0; s < 4; s++) {
            const int k = kteam * 128 + s * 32 + lk * 8;
            const float* p = W_ih + (size_t)j * IN + k;
            us8 u;
            #pragma unroll
            for (int e = 0; e < 8; e++) u[e] = f2bf(p[e]);
            wih[nt][s] = __builtin_bit_cast(bf16x8, u);
        }
        #pragma unroll
        for (int s = 0; s < 8; s++) {
            const int k = kteam * 256 + s * 32 + lk * 8;
            const float* p = W_hh + (size_t)j * HID + k;
            us8 u;
            #pragma unroll
            for (int e = 0; e < 8; e++) u[e] = f2bf(p[e]);
            whh[nt][s] = __builtin_bit_cast(bf16x8, u);
        }
    }
    if (tid < 64) biasS[tid] = b_ih[c0 + tid] + b_hh[c0 + tid];

    unsigned int* grp_flags = flags + g * 16;
    unsigned int* my_flag   = grp_flags + w;

    // h chunks (16B): 16 rows x 128 chunks / 512 thr = 4 each (R6-proven)
    int hgoff[4], hloff[4];
    #pragma unroll
    for (int it = 0; it < 4; it++) {
        const int c    = tid + it * 512;
        const int row  = c >> 7;
        const int colc = c & 127;
        hgoff[it] = row * 2048 + colc * 16;
        hloff[it] = row * 2048 + ((colc * 16) ^ ((row & 7) << 4));
    }
    // x chunks (16B): 16 rows x 64 chunks / 512 thr = 2 each (R6-proven)
    const int xrow[2] = { (tid) >> 6, (tid + 512) >> 6 };
    const int xcol[2] = { (tid) & 63, (tid + 512) & 63 };

    // ---- prologue: load + convert x(0) ----
    us8 xbf[2];
    {
        const float* xsrc = seqs + (size_t)gr0 * IN;
        #pragma unroll
        for (int it = 0; it < 2; it++) {
            const float* s4 = xsrc + xrow[it] * IN + xcol[it] * 8;
            float4 a = *reinterpret_cast<const float4*>(s4);
            float4 b = *reinterpret_cast<const float4*>(s4 + 4);
            us8 u;
            u[0]=f2bf(a.x); u[1]=f2bf(a.y); u[2]=f2bf(a.z); u[3]=f2bf(a.w);
            u[4]=f2bf(b.x); u[5]=f2bf(b.y); u[6]=f2bf(b.z); u[7]=f2bf(b.w);
            xbf[it] = u;
        }
    }

    const size_t slotB = (size_t)BATCH * HID * 2;   // 256KB per ring slot
    char* hbase = reinterpret_cast<char*>(hbuf);

    for (int t = 0; t < T_STEPS; t++) {
        // 1: write prepared x(t) -> xtile (swizzled)
        #pragma unroll
        for (int it = 0; it < 2; it++) {
            const int off = xrow[it] * 1024 + ((xcol[it] * 16) ^ ((xrow[it] & 7) << 4));
            *reinterpret_cast<us8*>(reinterpret_cast<char*>(xtile) + off) = xbf[it];
        }

        // 2: flag spin — wave0, 16 lanes (R4 protocol)
        if (t > 0 && wv == 0 && lane < 16) {
            const unsigned int* f = grp_flags + lane;
            while (__hip_atomic_load(f, __ATOMIC_RELAXED, __HIP_MEMORY_SCOPE_AGENT) < (unsigned)t) { }
        }
        __syncthreads();   // B1: xtile visible; h(t) certified at LLC

        // 3: issue 4 agent h-loads (oldest), then 4 pinned x(t+1) loads
        ui4 hv[4];
        const char* hsrc = hbase + (size_t)(t & 1) * slotB + (size_t)gr0 * 2048;
        if (t > 0) {
            #pragma unroll
            for (int it = 0; it < 4; it++) hv[it] = ld_u128_agent(hsrc + hgoff[it]);
        }
        __builtin_amdgcn_sched_barrier(0);
        float4 xr[4];
        {
            const int tn = (t + 1 < T_STEPS) ? t + 1 : t;
            const float* xn = seqs + (size_t)tn * (BATCH * IN) + (size_t)gr0 * IN;
            #pragma unroll
            for (int it = 0; it < 2; it++) {
                const float* s4 = xn + xrow[it] * IN + xcol[it] * 8;
                xr[2*it]   = ld_f128(s4);
                xr[2*it+1] = ld_f128(s4 + 4);
            }
        }
        __builtin_amdgcn_sched_barrier(0);

        // 4: x-projection MFMAs (overlap h-load round trip)
        f32x4 acc0 = {0.f, 0.f, 0.f, 0.f};
        f32x4 acc1 = {0.f, 0.f, 0.f, 0.f};
        {
            const int kx0b = kteam * 256;
            #pragma unroll
            for (int s = 0; s < 4; s++) {
                bf16x8 a = ld_frag(xtile, ln15, kx0b + s * 64 + lk * 16, 1024);
                acc0 = __builtin_amdgcn_mfma_f32_16x16x32_bf16(a, wih[0][s], acc0, 0, 0, 0);
                acc1 = __builtin_amdgcn_mfma_f32_16x16x32_bf16(a, wih[1][s], acc1, 0, 0, 0);
            }
        }

        if (t > 0) {
            // 5: claim ONLY the h loads (4 x loads stay in flight), stage htile
            asm volatile("s_waitcnt vmcnt(4)" ::: "memory");
            __builtin_amdgcn_sched_barrier(0);
            #pragma unroll
            for (int it = 0; it < 4; it++) {
                *reinterpret_cast<ui4*>(reinterpret_cast<char*>(htile) + hloff[it]) = hv[it];
            }
            __syncthreads();   // B2: htile staged

            // 6: recurrence MFMAs
            const int kh0b = kteam * 512;
            #pragma unroll
            for (int s = 0; s < 8; s++) {
                bf16x8 a = ld_frag(htile, ln15, kh0b + s * 64 + lk * 16, 2048);
                acc0 = __builtin_amdgcn_mfma_f32_16x16x32_bf16(a, whh[0][s], acc0, 0, 0, 0);
                acc1 = __builtin_amdgcn_mfma_f32_16x16x32_bf16(a, whh[1][s], acc1, 0, 0, 0);
            }
        }

        // 7: K-team partials
        #pragma unroll
        for (int r = 0; r < 4; r++) {
            red[kteam][lk * 4 + r][chalf * 32 + ln15]      = acc0[r];
            red[kteam][lk * 4 + r][chalf * 32 + 16 + ln15] = acc1[r];
        }
        __syncthreads();   // B3

        // 8: reduce + bias + relu
        const int hrow = tid >> 5;          // 0..15
        const int co2  = (tid & 31) * 2;    // even col within 64-col slice
        float v0 = red[0][hrow][co2]   + red[1][hrow][co2]   + red[2][hrow][co2]   + red[3][hrow][co2]   + biasS[co2];
        float v1 = red[0][hrow][co2+1] + red[1][hrow][co2+1] + red[2][hrow][co2+1] + red[3][hrow][co2+1] + biasS[co2+1];
        v0 = fmaxf(v0, 0.0f);
        v1 = fmaxf(v1, 0.0f);

        // 9: claim x(t+1) (only x loads outstanding), convert — R4 ordering
        asm volatile("s_waitcnt vmcnt(0)" ::: "memory");
        __builtin_amdgcn_sched_barrier(0);
        #pragma unroll
        for (int it = 0; it < 2; it++) {
            float4 a = xr[2*it], b = xr[2*it+1];
            us8 u;
            u[0]=f2bf(a.x); u[1]=f2bf(a.y); u[2]=f2bf(a.z); u[3]=f2bf(a.w);
            u[4]=f2bf(b.x); u[5]=f2bf(b.y); u[6]=f2bf(b.z); u[7]=f2bf(b.w);
            xbf[it] = u;
        }

        // 10: store H_{t+1} (bf16 ring; fp32 hfinal at last step)
        if (t < T_STEPS - 1) {
            unsigned pack = (unsigned)f2bf(v0) | ((unsigned)f2bf(v1) << 16);
            unsigned* dst = reinterpret_cast<unsigned*>(
                hbase + (size_t)((t + 1) & 1) * slotB
                + ((size_t)(gr0 + hrow) * HID + c0 + co2) * 2);
            __hip_atomic_store(dst, pack, __ATOMIC_RELAXED, __HIP_MEMORY_SCOPE_AGENT);
        } else {
            unsigned long long pack = ((unsigned long long)__float_as_uint(v1) << 32) | __float_as_uint(v0);
            unsigned long long* dst = reinterpret_cast<unsigned long long*>(
                hfinal + (size_t)(gr0 + hrow) * HID + c0 + co2);
            __hip_atomic_store(dst, pack, __ATOMIC_RELAXED, __HIP_MEMORY_SCOPE_AGENT);
        }

        // 11: drain -> barrier -> flag (R4 protocol, writer-side certificate)
        asm volatile("s_waitcnt vmcnt(0)" ::: "memory");
        __builtin_amdgcn_sched_barrier(0);
        __syncthreads();   // B4: every thread's store drained
        if (tid == 0) {
            __hip_atomic_store(my_flag, (unsigned)(t + 1), __ATOMIC_RELAXED, __HIP_MEMORY_SCOPE_AGENT);
        }
    }

    // ---- final group barrier, then fused FC: out = hfinal @ W_fc^T + b_fc ----
    if (wv == 0 && lane < 16) {
        const unsigned int* f = grp_flags + lane;
        while (__hip_atomic_load(f, __ATOMIC_RELAXED, __HIP_MEMORY_SCOPE_AGENT) < (unsigned)T_STEPS) {
            __builtin_amdgcn_s_sleep(1);
        }
    }
    __syncthreads();
    __threadfence();   // acquire: plain loads below see peers' hfinal

    {
        // WG computes out[gr0..gr0+15][w*16..w*16+15]; 2-way K-split, 512 thr
        const int oi   = tid & 255;
        const int half = tid >> 8;
        const int row  = oi >> 4;
        const int oc   = oi & 15;
        const int o    = w * 16 + oc;
        const float* hv2 = hfinal + (size_t)(gr0 + row) * HID + half * 512;
        const float* wf  = W_fc  + (size_t)o * HID + half * 512;
        float sum = 0.f;
        #pragma unroll 4
        for (int k = 0; k < 512; k += 4) {
            float4 hh = *reinterpret_cast<const float4*>(hv2 + k);
            float4 ww = *reinterpret_cast<const float4*>(wf + k);
            sum += hh.x * ww.x + hh.y * ww.y + hh.z * ww.z + hh.w * ww.w;
        }
        float* redf = &red[0][0][0];
        redf[tid] = sum;
        __syncthreads();
        if (tid < 256) {
            const int row2 = tid >> 4;
            const int oc2  = tid & 15;
            out[(size_t)(gr0 + row2) * OUTN + w * 16 + oc2] =
                redf[tid] + redf[tid + 256] + b_fc[w * 16 + oc2];
        }
    }
}

extern "C" void kernel_launch(void* const* d_in, const int* in_sizes, int n_in,
                              void* d_out, int out_size, void* d_ws, size_t ws_size,
                              hipStream_t stream) {
    const float* seqs = (const float*)d_in[0];
    const float* W_ih = (const float*)d_in[1];
    const float* W_hh = (const float*)d_in[2];
    const float* b_ih = (const float*)d_in[3];
    const float* b_hh = (const float*)d_in[4];
    const float* W_fc = (const float*)d_in[5];
    const float* b_fc = (const float*)d_in[6];
    float* out = (float*)d_out;

    char* ws = (char*)d_ws;
    unsigned short* hbuf   = (unsigned short*)ws;                 // 2*128*1024*2 = 524288 B
    float*          hfinal = (float*)(ws + 524288);               // 128*1024*4   = 524288 B
    unsigned int*   flags  = (unsigned int*)(ws + 1048576);       // 8*16*4       = 512 B

    hipMemsetAsync(flags, 0, 8 * 16 * sizeof(unsigned int), stream);
    rnn_persistent<<<dim3(128), dim3(512), 0, stream>>>(
        seqs, W_ih, W_hh, b_ih, b_hh, W_fc, b_fc, out, hbuf, hfinal, flags);
}